// Round 5
// baseline (2005.730 us; speedup 1.0000x reference)
//
#include <hip/hip_runtime.h>
#include <hip/hip_fp16.h>
#include <math.h>

// TVNet ADMM: 10 iterations of {w1 conv -> FFT solve -> soft-threshold update}.
// otf = 1 + sum rho|K_hat|^2 is real & even -> precompute 1/(otf*N^2) once;
// pack image pairs (2b,2b+1) as re/im of one complex FFT (real-even multiplier
// preserves the packing exactly, by linearity). Forward = DIF (natural->bitrev),
// inverse = DIT (bitrev->natural): zero bit-reversal permutes; rotf stored at
// bit-reversed coordinates. 3 FFT passes/solve: fwd-x (transposing), fused
// {fwd-y, x rotf, inv-y} (transposing), inv-x (row-writing, optional unpack).
// State: mu (|mu|<=gamma<=0.2) and d = p-mu, both fp16 (d is derived state, no
// error accumulation). d_out doubles as FFT ping buffer. WS need: 154.1 MB.

namespace {
constexpr int C_ = 3, KO_ = 2, G_ = 6, N_ = 512, NITER_ = 10, P2_ = 8;
constexpr size_t IMG = (size_t)N_ * N_;              // 262144
constexpr size_t IMGPAIR = (size_t)P2_ * C_ * IMG;   // 6.29M complex
constexpr size_t GIMG = (size_t)P2_ * G_ * IMG;      // 12.58M
constexpr float TWO_PI = 6.28318530717958647692f;
__device__ __forceinline__ int brev9(int v) { return (int)(__brev((unsigned)v) >> 23); }
} // namespace

// Butterfly macros over shared re/im[8][513], 256 threads = 256 butterflies/row.
#define DIF_STAGES(WR, WI)                                                   \
  _Pragma("unroll")                                                          \
  for (int len = 512; len >= 2; len >>= 1) {                                 \
    __syncthreads();                                                         \
    const int half = len >> 1;                                               \
    const int pos = t & (half - 1);                                          \
    const int i0 = ((t ^ pos) << 1) | pos;                                   \
    const int i1 = i0 + half;                                                \
    const int twidx = pos * (512 / len);                                     \
    const float wr = (WR), wi_ = (WI);                                       \
    _Pragma("unroll")                                                        \
    for (int q = 0; q < 8; ++q) {                                            \
      float ar = re[q][i0], ai = im[q][i0];                                  \
      float br = re[q][i1], bi = im[q][i1];                                  \
      re[q][i0] = ar + br; im[q][i0] = ai + bi;                              \
      float dr = ar - br, di = ai - bi;                                      \
      re[q][i1] = wr * dr - wi_ * di;                                        \
      im[q][i1] = wr * di + wi_ * dr;                                        \
    }                                                                        \
  }

#define DIT_STAGES(WR, WI)                                                   \
  _Pragma("unroll")                                                          \
  for (int len = 2; len <= 512; len <<= 1) {                                 \
    __syncthreads();                                                         \
    const int half = len >> 1;                                               \
    const int pos = t & (half - 1);                                          \
    const int i0 = ((t ^ pos) << 1) | pos;                                   \
    const int i1 = i0 + half;                                                \
    const int twidx = pos * (512 / len);                                     \
    const float wr = (WR), wi_ = (WI);                                       \
    _Pragma("unroll")                                                        \
    for (int q = 0; q < 8; ++q) {                                            \
      float br = re[q][i1], bi = im[q][i1];                                  \
      float xr = wr * br - wi_ * bi;                                         \
      float xi = wr * bi + wi_ * br;                                         \
      float ar = re[q][i0], ai = im[q][i0];                                  \
      re[q][i0] = ar + xr; im[q][i0] = ai + xi;                              \
      re[q][i1] = ar - xr; im[q][i1] = ai - xi;                              \
    }                                                                        \
  }

// ---- pass 1: forward DIF along x, transposed write: [y][x] -> [px][y] ------
__global__ __launch_bounds__(256) void fftX_fwd(
    const float2* __restrict__ in, float2* __restrict__ out)
{
  __shared__ float re[8][513], im[8][513];
  __shared__ float twr[256], twi[256];
  const int t = threadIdx.x;
  const int pi = blockIdx.y;
  const int r0 = blockIdx.x << 3;
  { float s, c; sincosf(-TWO_PI * (float)t * (1.0f / 512.0f), &s, &c); twr[t] = c; twi[t] = s; }
  const float2* src = in + (size_t)pi * IMG + (size_t)r0 * N_;
  #pragma unroll
  for (int k = 0; k < 16; ++k) {
    int f = t + (k << 8); int q = f >> 9, e = f & 511;
    float2 v = src[f]; re[q][e] = v.x; im[q][e] = v.y;
  }
  DIF_STAGES(twr[twidx], twi[twidx])
  __syncthreads();
  const size_t ob = (size_t)pi * IMG;
  #pragma unroll
  for (int k = 0; k < 16; ++k) {
    int f = t + (k << 8); int e = f >> 3, q = f & 7;  // 8 lanes -> one 64B line
    out[ob + (size_t)e * N_ + (r0 + q)] = make_float2(re[q][e], im[q][e]);
  }
}

// ---- pass 2 (fused): fwd DIF-y, multiply 1/(otf*N^2), inv DIT-y ------------
// in [px][y] -> out [y][px].  rotf layout [px][py] (both bit-reversed coords).
__global__ __launch_bounds__(256) void fftY_mid(
    const float2* __restrict__ in, float2* __restrict__ out,
    const float* __restrict__ rotf)
{
  __shared__ float re[8][513], im[8][513];
  __shared__ float twr[256], twi[256];
  const int t = threadIdx.x;
  const int pi = blockIdx.y;
  const int c = pi % 3;
  const int r0 = blockIdx.x << 3;  // px rows
  { float s, cc; sincosf(-TWO_PI * (float)t * (1.0f / 512.0f), &s, &cc); twr[t] = cc; twi[t] = s; }
  const float2* src = in + (size_t)pi * IMG + (size_t)r0 * N_;
  #pragma unroll
  for (int k = 0; k < 16; ++k) {
    int f = t + (k << 8); int q = f >> 9, e = f & 511;
    float2 v = src[f]; re[q][e] = v.x; im[q][e] = v.y;
  }
  DIF_STAGES(twr[twidx], twi[twidx])
  __syncthreads();
  const float* rc = rotf + (size_t)c * IMG + (size_t)r0 * N_;
  #pragma unroll
  for (int k = 0; k < 16; ++k) {
    int f = t + (k << 8); int q = f >> 9, e = f & 511;
    float sc = rc[(size_t)q * N_ + e];
    re[q][e] *= sc; im[q][e] *= sc;
  }
  DIT_STAGES(twr[twidx], -twi[twidx])   // conjugate twiddles = inverse
  __syncthreads();
  const size_t ob = (size_t)pi * IMG;
  #pragma unroll
  for (int k = 0; k < 16; ++k) {
    int f = t + (k << 8); int e = f >> 3, q = f & 7;
    out[ob + (size_t)e * N_ + (r0 + q)] = make_float2(re[q][e], im[q][e]);
  }
}

// ---- pass 3: inverse DIT along x, row write: [y][px] -> [y][x] -------------
template<int UNPACK>
__global__ __launch_bounds__(256) void fftX_inv(
    const float2* __restrict__ in, void* __restrict__ out_)
{
  __shared__ float re[8][513], im[8][513];
  __shared__ float twr[256], twi[256];
  const int t = threadIdx.x;
  const int pi = blockIdx.y;
  const int r0 = blockIdx.x << 3;  // y rows
  { float s, c; sincosf(TWO_PI * (float)t * (1.0f / 512.0f), &s, &c); twr[t] = c; twi[t] = s; }
  const float2* src = in + (size_t)pi * IMG + (size_t)r0 * N_;
  #pragma unroll
  for (int k = 0; k < 16; ++k) {
    int f = t + (k << 8); int q = f >> 9, e = f & 511;
    float2 v = src[f]; re[q][e] = v.x; im[q][e] = v.y;
  }
  DIT_STAGES(twr[twidx], twi[twidx])
  __syncthreads();
  if (!UNPACK) {
    float2* out = (float2*)out_;
    const size_t ob = (size_t)pi * IMG;
    #pragma unroll
    for (int k = 0; k < 16; ++k) {
      int f = t + (k << 8); int q = f >> 9, e = f & 511;  // row-major, coalesced
      out[ob + (size_t)(r0 + q) * N_ + e] = make_float2(re[q][e], im[q][e]);
    }
  } else {
    float* outf = (float*)out_;
    const int b2 = pi / 3, c = pi % 3;
    const size_t b0 = ((size_t)(2 * b2) * C_ + c) * IMG;
    const size_t b1 = ((size_t)(2 * b2 + 1) * C_ + c) * IMG;
    #pragma unroll
    for (int k = 0; k < 16; ++k) {
      int f = t + (k << 8); int q = f >> 9, e = f & 511;
      size_t idx = (size_t)(r0 + q) * N_ + e;
      outf[b0 + idx] = re[q][e];
      outf[b1 + idx] = im[q][e];
    }
  }
}

// --------- 1/(otf*N^2) at bit-reversed (px, py) coordinates -----------------
__global__ __launch_bounds__(256) void rotf_kernel(
    const float* __restrict__ kerK, const float* __restrict__ rho,
    float* __restrict__ rotf)
{
  const int p = blockIdx.x * 256 + threadIdx.x;
  const int c = blockIdx.y;
  const int fx = brev9(p >> 9);    // x-frequency (axis -1)
  const int fy = brev9(p & 511);   // y-frequency (axis -2)
  float sy, cy, sx, cx;
  sincosf(-TWO_PI * (float)fy * (1.0f / 512.0f), &sy, &cy);
  sincosf(-TWO_PI * (float)fx * (1.0f / 512.0f), &sx, &cx);
  const float pyr[3] = {cy, 1.f, cy}, pyi[3] = {-sy, 0.f, sy};
  const float pxr[3] = {cx, 1.f, cx}, pxi[3] = {-sx, 0.f, sx};
  float acc = 0.f;
  for (int o = 0; o < KO_; ++o) {
    const int g = c * KO_ + o;
    float kr = 0.f, ki = 0.f;
    #pragma unroll
    for (int ky = 0; ky < 3; ++ky)
      #pragma unroll
      for (int kx = 0; kx < 3; ++kx) {
        float kv = kerK[g * 9 + ky * 3 + kx];
        float pr = pyr[ky] * pxr[kx] - pyi[ky] * pxi[kx];
        float pim = pyr[ky] * pxi[kx] + pyi[ky] * pxr[kx];
        kr += kv * pr; ki += kv * pim;
      }
    acc += rho[g] * (kr * kr + ki * ki);  // |K_hat|^2: linear phase drops out
  }
  rotf[(size_t)c * IMG + p] = 1.f / ((1.f + acc) * (float)(N_ * N_));
}

// ------------------------------ iter 0: w1 = x ------------------------------
__global__ __launch_bounds__(256) void pack_kernel(
    const float* __restrict__ x, float2* __restrict__ w1c)
{
  const int p = blockIdx.x * 256 + threadIdx.x;
  const int c = blockIdx.y, b2 = blockIdx.z;
  const float* x0 = x + ((size_t)(2 * b2) * C_ + c) * IMG;
  const float* x1 = x + ((size_t)(2 * b2 + 1) * C_ + c) * IMG;
  w1c[((size_t)b2 * C_ + c) * IMG + p] = make_float2(x0[p], x1[p]);
}

// -------- w1 = x + sum_o conv_circ(d_g, rho*flip(kerK_g)), d in fp16 --------
__global__ __launch_bounds__(256) void w1_kernel(
    const float* __restrict__ x, const __half2* __restrict__ d,
    const float* __restrict__ kerK, const float* __restrict__ rho,
    float2* __restrict__ w1c)
{
  const int p = blockIdx.x * 256 + threadIdx.x;
  const int c = blockIdx.y, b2 = blockIdx.z;
  const int y = p >> 9, xx = p & 511;
  const int ys[3] = {(y + 511) & 511, y, (y + 1) & 511};
  const int xs[3] = {(xx + 511) & 511, xx, (xx + 1) & 511};
  const float* x0 = x + ((size_t)(2 * b2) * C_ + c) * IMG;
  const float* x1 = x + ((size_t)(2 * b2 + 1) * C_ + c) * IMG;
  float s0 = x0[p], s1 = x1[p];
  #pragma unroll
  for (int o = 0; o < KO_; ++o) {
    const int g = c * KO_ + o;
    const float rg = rho[g];
    const __half2* dg = d + ((size_t)b2 * G_ + g) * IMG;
    #pragma unroll
    for (int i = 0; i < 3; ++i)
      #pragma unroll
      for (int j = 0; j < 3; ++j) {
        float wgt = rg * kerK[g * 9 + (2 - i) * 3 + (2 - j)];  // adjoint = flipped
        float2 v = __half22float2(dg[(size_t)ys[i] * N_ + xs[j]]);
        s0 += v.x * wgt; s1 += v.y * wgt;
      }
  }
  w1c[((size_t)b2 * C_ + c) * IMG + p] = make_float2(s0, s1);
}

// --- c = corr(u,kerK); t = c+mu; p' = soft(t); mu' = t-p'; d' = 2p'-t (fp16) --
__global__ __launch_bounds__(256) void update_kernel(
    const float2* __restrict__ uc, const float* __restrict__ kerK,
    const float* __restrict__ gamma, __half2* __restrict__ mu,
    __half2* __restrict__ d)
{
  const int p = blockIdx.x * 256 + threadIdx.x;
  const int c = blockIdx.y, b2 = blockIdx.z;
  const int y = p >> 9, xx = p & 511;
  const int ys[3] = {(y + 511) & 511, y, (y + 1) & 511};
  const int xs[3] = {(xx + 511) & 511, xx, (xx + 1) & 511};
  const float2* u = uc + ((size_t)b2 * C_ + c) * IMG;
  float2 tv[3][3];
  #pragma unroll
  for (int i = 0; i < 3; ++i)
    #pragma unroll
    for (int j = 0; j < 3; ++j)
      tv[i][j] = u[(size_t)ys[i] * N_ + xs[j]];
  #pragma unroll
  for (int o = 0; o < KO_; ++o) {
    const int g = c * KO_ + o;
    float cc0 = 0.f, cc1 = 0.f;
    #pragma unroll
    for (int i = 0; i < 3; ++i)
      #pragma unroll
      for (int j = 0; j < 3; ++j) {
        float wgt = kerK[g * 9 + i * 3 + j];  // cross-correlation
        cc0 += tv[i][j].x * wgt;
        cc1 += tv[i][j].y * wgt;
      }
    const size_t gi = ((size_t)b2 * G_ + g) * IMG + p;
    float2 m = __half22float2(mu[gi]);
    float t0 = cc0 + m.x, t1 = cc1 + m.y;
    float gam = gamma[g];
    float a0 = fabsf(t0) - gam;
    float a1 = fabsf(t1) - gam;
    float p0 = a0 > 0.f ? copysignf(a0, t0) : 0.f;
    float p1 = a1 > 0.f ? copysignf(a1, t1) : 0.f;
    mu[gi] = __floats2half2_rn(t0 - p0, t1 - p1);      // |mu| <= gamma <= 0.2
    d[gi] = __floats2half2_rn(2.f * p0 - t0, 2.f * p1 - t1);
  }
}

// ws too small -> unmistakable sentinel in out[0]
__global__ void sentinel_kernel(float* out) { out[0] = 1.2e7f; }

extern "C" void kernel_launch(void* const* d_in, const int* in_sizes, int n_in,
                              void* d_out, int out_size, void* d_ws, size_t ws_size,
                              hipStream_t stream)
{
  const float* x     = (const float*)d_in[0];  // (16,3,512,512)
  const float* kerK  = (const float*)d_in[1];  // (6,1,3,3)
  const float* gamma = (const float*)d_in[2];  // (1,6,1,1)
  const float* rho   = (const float*)d_in[3];  // (6,1,1,1)
  float* out = (float*)d_out;
  float2* T0 = (float2*)d_out;  // d_out doubles as FFT ping buffer (exact size)

  const size_t bufA_b = IMGPAIR * sizeof(float2);   // 50.33 MB
  const size_t d_b    = GIMG * sizeof(__half2);     // 50.33 MB
  const size_t rotf_b = (size_t)C_ * IMG * sizeof(float);  // 3.15 MB
  const size_t mu_b   = GIMG * sizeof(__half2);     // 50.33 MB
  const size_t need = bufA_b + d_b + rotf_b + mu_b; // 154.1 MB

  if (ws_size < need) { sentinel_kernel<<<1, 1, 0, stream>>>(out); return; }

  char* w = (char*)d_ws;
  float2*  bufA  = (float2*)w;  w += bufA_b;
  __half2* dbuf  = (__half2*)w; w += d_b;
  float*   rotf  = (float*)w;   w += rotf_b;
  __half2* mubuf = (__half2*)w;

  hipMemsetAsync(mubuf, 0, mu_b, stream);  // mu = 0 (d never read at iter 0)

  const dim3 blk(256);
  const dim3 gridPix(1024, C_, P2_);
  const dim3 gridFFT(N_ / 8, P2_ * C_);

  rotf_kernel<<<dim3(1024, C_), blk, 0, stream>>>(kerK, rho, rotf);

  for (int it = 0; it < NITER_; ++it) {
    if (it == 0)
      pack_kernel<<<gridPix, blk, 0, stream>>>(x, bufA);
    else
      w1_kernel<<<gridPix, blk, 0, stream>>>(x, dbuf, kerK, rho, bufA);
    fftX_fwd<<<gridFFT, blk, 0, stream>>>(bufA, T0);        // [y][x] -> [px][y]
    fftY_mid<<<gridFFT, blk, 0, stream>>>(T0, bufA, rotf);  // -> [y][px], filtered
    if (it < NITER_ - 1) {
      fftX_inv<0><<<gridFFT, blk, 0, stream>>>(bufA, (void*)T0);  // u in T0
      update_kernel<<<gridPix, blk, 0, stream>>>(T0, kerK, gamma, mubuf, dbuf);
    } else {
      fftX_inv<1><<<gridFFT, blk, 0, stream>>>(bufA, (void*)out); // unpack to out
    }
  }
}

// Round 7
// 1451.683 us; speedup vs baseline: 1.3817x; 1.3817x over previous
//
#include <hip/hip_runtime.h>
#include <hip/hip_fp16.h>
#include <math.h>

// TVNet ADMM, radix-8 FFT edition.
// Solve u = ifft2( fft2(w1) * rotf ) with rotf = 1/((1+sum rho|K^|^2)*N^2),
// real & even -> image pairs packed as complex stay exact. FFT 512 = 8^3:
// 3 register stages (DIF fwd: natural->digit-rev; DIT inv: digit-rev->natural,
// zero reordering anywhere; rotf stored at digit-reversed coords). Each thread
// owns 8 complex values; LDS only for the 2 inter-stage exchanges (+ transpose
// epilogue). LDS bank swizzle: col = (r + 3j + 8q)&63 per 64-block j, row q
// (wave==row so +8q is free for compute stages, and makes the cross-row
// transposed epilogue conflict-free). Syncs per pass: 3 / 5 / 2 (was 10/19/10).
// State: mu, d=p-mu in fp16 (|mu|<=gamma<=0.2; d is derived, no accumulation).
// d_out doubles as the FFT ping buffer. WS need: 154.1 MB.

namespace {
constexpr int C_ = 3, KO_ = 2, G_ = 6, N_ = 512, NITER_ = 10, P2_ = 8;
constexpr size_t IMG = (size_t)N_ * N_;
constexpr size_t IMGPAIR = (size_t)P2_ * C_ * IMG;
constexpr size_t GIMG = (size_t)P2_ * G_ * IMG;
constexpr float TWO_PI = 6.28318530717958647692f;

__device__ __forceinline__ int drev9(int v) {  // digit-reverse base 8, 3 digits
  return ((v & 7) << 6) | (v & 56) | ((v >> 6) & 7);
}
__device__ __forceinline__ float2 cadd(float2 a, float2 b){ return make_float2(a.x+b.x, a.y+b.y); }
__device__ __forceinline__ float2 csub(float2 a, float2 b){ return make_float2(a.x-b.x, a.y-b.y); }
__device__ __forceinline__ float2 cmul(float2 a, float2 b){ return make_float2(a.x*b.x - a.y*b.y, a.x*b.y + a.y*b.x); }
template<int INV> __device__ __forceinline__ float2 rotm(float2 d){  // * -i (fwd) / * +i (inv)
  return INV ? make_float2(-d.y, d.x) : make_float2(d.y, -d.x);
}

// 8-point DFT, v natural in; out: v[idx] holds X[brev3(idx)]
template<int INV>
__device__ __forceinline__ void dft8(float2 v[8]) {
  constexpr float SQ = 0.70710678118654752440f;
  float2 a0=cadd(v[0],v[4]), d0=csub(v[0],v[4]);
  float2 a1=cadd(v[1],v[5]), d1=csub(v[1],v[5]);
  float2 a2=cadd(v[2],v[6]), d2=csub(v[2],v[6]);
  float2 a3=cadd(v[3],v[7]), d3=csub(v[3],v[7]);
  float2 b5 = INV ? make_float2(SQ*(d1.x-d1.y), SQ*(d1.y+d1.x))
                  : make_float2(SQ*(d1.x+d1.y), SQ*(d1.y-d1.x));
  float2 b6 = rotm<INV>(d2);
  float2 b7 = INV ? make_float2(-SQ*(d3.x+d3.y), SQ*(d3.x-d3.y))
                  : make_float2(SQ*(d3.y-d3.x), -SQ*(d3.x+d3.y));
  float2 c0=cadd(a0,a2), c2=csub(a0,a2);
  float2 c1=cadd(a1,a3), c3=rotm<INV>(csub(a1,a3));
  float2 c4=cadd(d0,b6), c6=csub(d0,b6);
  float2 c5=cadd(b5,b7), c7=rotm<INV>(csub(b5,b7));
  v[0]=cadd(c0,c1); v[1]=csub(c0,c1);
  v[2]=cadd(c2,c3); v[3]=csub(c2,c3);
  v[4]=cadd(c4,c5); v[5]=csub(c4,c5);
  v[6]=cadd(c6,c7); v[7]=csub(c6,c7);
}

// LDS layout: rows q (0..7) of 512; storage s -> block j=s>>6, rotated col.
__device__ __forceinline__ int laddr(int s, int q) {
  return (q << 9) | (s & 448) | ((s + 3 * (s >> 6) + (q << 3)) & 63);
}
__device__ __forceinline__ void lstore(float* lre, float* lim, int q, int s, float2 v){
  int a = laddr(s, q); lre[a] = v.x; lim[a] = v.y;
}
__device__ __forceinline__ float2 lload(const float* lre, const float* lim, int q, int s){
  int a = laddr(s, q); return make_float2(lre[a], lim[a]);
}

// forward stages 1..2 (global strided read -> LDS holds stage-2 output), +sync
__device__ __forceinline__ void fwd_stage12(const float2* __restrict__ src,
                                            float* lre, float* lim, int t, int q) {
  constexpr int RB[8] = {0,4,2,6,1,5,3,7};
  float2 v[8];
  #pragma unroll
  for (int m=0;m<8;++m) v[m] = src[t + (m<<6)];
  dft8<0>(v);
  float sn, cs; sincosf(-TWO_PI * (1.0f/512.0f) * (float)t, &sn, &cs);
  float2 w = make_float2(cs, sn), tw = make_float2(1.f, 0.f);
  #pragma unroll
  for (int j=0;j<8;++j){ lstore(lre,lim,q,(j<<6)+t, cmul(v[RB[j]], tw)); tw = cmul(tw, w); }
  __syncthreads();
  const int jb = t >> 3, n1 = t & 7;
  #pragma unroll
  for (int m=0;m<8;++m) v[m] = lload(lre,lim,q,(jb<<6) + n1 + (m<<3));
  dft8<0>(v);
  sincosf(-TWO_PI * (1.0f/64.0f) * (float)n1, &sn, &cs);
  w = make_float2(cs, sn); tw = make_float2(1.f, 0.f);
  #pragma unroll
  for (int j2=0;j2<8;++j2){ lstore(lre,lim,q,(jb<<6)+(j2<<3)+n1, cmul(v[RB[j2]], tw)); tw = cmul(tw, w); }
  __syncthreads();
}

// inverse middle stage (LDS -> LDS), caller syncs around it
__device__ __forceinline__ void inv_stageB(float* lre, float* lim, int t, int q) {
  constexpr int RB[8] = {0,4,2,6,1,5,3,7};
  const int jb = t >> 3, n1 = t & 7;
  float sn, cs; sincosf(TWO_PI * (1.0f/64.0f) * (float)n1, &sn, &cs);
  float2 w = make_float2(cs, sn), tw = make_float2(1.f, 0.f);
  float2 v[8];
  #pragma unroll
  for (int j2=0;j2<8;++j2){ v[j2] = cmul(lload(lre,lim,q,(jb<<6)+n1+(j2<<3)), tw); tw = cmul(tw, w); }
  dft8<1>(v);
  #pragma unroll
  for (int n2=0;n2<8;++n2) lstore(lre,lim,q,(jb<<6)+(n2<<3)+n1, v[RB[n2]]);
}

// inverse last stage: LDS -> registers, natural order o[n3] = x[t + 64*n3]
__device__ __forceinline__ void inv_stageC(const float* lre, const float* lim,
                                           int t, int q, float2 o[8]) {
  constexpr int RB[8] = {0,4,2,6,1,5,3,7};
  float sn, cs; sincosf(TWO_PI * (1.0f/512.0f) * (float)t, &sn, &cs);
  float2 w = make_float2(cs, sn), tw = make_float2(1.f, 0.f);
  float2 v[8];
  #pragma unroll
  for (int j=0;j<8;++j){ v[j] = cmul(lload(lre,lim,q,(j<<6)+t), tw); tw = cmul(tw, w); }
  dft8<1>(v);
  #pragma unroll
  for (int n3=0;n3<8;++n3) o[n3] = v[RB[n3]];
}
} // namespace

// ---- pass 1: fwd-x, [y][x] natural -> T0[sx][y] (transposed, digit-rev sx) ----
__global__ __launch_bounds__(512) void r8_fwdX(
    const float2* __restrict__ in, float2* __restrict__ out)
{
  __shared__ float lre[4096], lim[4096];
  const int tid = threadIdx.x, q = tid >> 6, t = tid & 63;
  const int pi = blockIdx.y, r0 = blockIdx.x << 3;
  constexpr int RB[8] = {0,4,2,6,1,5,3,7};
  const float2* src = in + (size_t)pi * IMG + (size_t)(r0 + q) * N_;
  fwd_stage12(src, lre, lim, t, q);
  float2 v[8];
  #pragma unroll
  for (int m=0;m<8;++m) v[m] = lload(lre,lim,q,(t<<3)+m);
  dft8<0>(v);
  #pragma unroll
  for (int k=0;k<8;++k) lstore(lre,lim,q,(t<<3)+k, v[RB[k]]);   // same slots, thread-exclusive
  __syncthreads();
  const int eq = tid & 7, e0 = tid >> 3;
  const size_t ob = (size_t)pi * IMG;
  #pragma unroll
  for (int kk=0;kk<8;++kk){
    int e = e0 + (kk<<6);
    int a = laddr(e, eq);
    out[ob + (size_t)e * N_ + r0 + eq] = make_float2(lre[a], lim[a]);
  }
}

// ---- pass 2: fwd-y, *rotf (in regs), inv-y; T0[px][y] -> bufA[y][px] ----
__global__ __launch_bounds__(512) void r8_mid(
    const float2* __restrict__ in, float2* __restrict__ out,
    const float* __restrict__ rotf)
{
  __shared__ float lre[4096], lim[4096];
  const int tid = threadIdx.x, q = tid >> 6, t = tid & 63;
  const int pi = blockIdx.y, r0 = blockIdx.x << 3;
  const int c = pi % 3;
  constexpr int RB[8] = {0,4,2,6,1,5,3,7};
  const float2* src = in + (size_t)pi * IMG + (size_t)(r0 + q) * N_;
  fwd_stage12(src, lre, lim, t, q);
  float2 v[8];
  #pragma unroll
  for (int m=0;m<8;++m) v[m] = lload(lre,lim,q,(t<<3)+m);
  dft8<0>(v);
  // filter at digit-reversed coords (row=px storage, col=py storage), in regs
  const float* rc = rotf + (size_t)c * IMG + (size_t)(r0 + q) * N_ + (t<<3);
  const float4 g0 = *(const float4*)rc, g1 = *(const float4*)(rc + 4);
  const float gg[8] = {g0.x,g0.y,g0.z,g0.w,g1.x,g1.y,g1.z,g1.w};
  float2 xk[8];
  #pragma unroll
  for (int k=0;k<8;++k) xk[k] = make_float2(v[RB[k]].x*gg[k], v[RB[k]].y*gg[k]);
  dft8<1>(xk);                      // inverse stage A, register-only handoff
  #pragma unroll
  for (int n1=0;n1<8;++n1) lstore(lre,lim,q,(t<<3)+n1, xk[RB[n1]]);
  __syncthreads();
  inv_stageB(lre, lim, t, q);
  __syncthreads();
  float2 o[8];
  inv_stageC(lre, lim, t, q, o);
  #pragma unroll
  for (int n3=0;n3<8;++n3) lstore(lre,lim,q,(n3<<6)+t, o[n3]);  // natural y, same slot set
  __syncthreads();
  const int eq = tid & 7, e0 = tid >> 3;
  const size_t ob = (size_t)pi * IMG;
  #pragma unroll
  for (int kk=0;kk<8;++kk){
    int e = e0 + (kk<<6);
    int a = laddr(e, eq);
    out[ob + (size_t)e * N_ + r0 + eq] = make_float2(lre[a], lim[a]);
  }
}

// ---- pass 3: inv-x; bufA[y][sx] -> [y][x] natural (UNPACK: split to planes) ----
template<int UNPACK>
__global__ __launch_bounds__(512) void r8_invX(
    const float2* __restrict__ in, void* __restrict__ out_)
{
  __shared__ float lre[4096], lim[4096];
  const int tid = threadIdx.x, q = tid >> 6, t = tid & 63;
  const int pi = blockIdx.y, r0 = blockIdx.x << 3;
  constexpr int RB[8] = {0,4,2,6,1,5,3,7};
  const float4* s4 = (const float4*)(in + (size_t)pi * IMG + (size_t)(r0 + q) * N_ + (t<<3));
  const float4 A0 = s4[0], A1 = s4[1], A2 = s4[2], A3 = s4[3];
  float2 v[8] = {make_float2(A0.x,A0.y), make_float2(A0.z,A0.w),
                 make_float2(A1.x,A1.y), make_float2(A1.z,A1.w),
                 make_float2(A2.x,A2.y), make_float2(A2.z,A2.w),
                 make_float2(A3.x,A3.y), make_float2(A3.z,A3.w)};
  dft8<1>(v);
  #pragma unroll
  for (int n1=0;n1<8;++n1) lstore(lre,lim,q,(t<<3)+n1, v[RB[n1]]);
  __syncthreads();
  inv_stageB(lre, lim, t, q);
  __syncthreads();
  float2 o[8];
  inv_stageC(lre, lim, t, q, o);
  if (!UNPACK) {
    float2* out = (float2*)out_;
    const size_t base = (size_t)pi * IMG + (size_t)(r0 + q) * N_ + t;
    #pragma unroll
    for (int n3=0;n3<8;++n3) out[base + (n3<<6)] = o[n3];
  } else {
    float* outf = (float*)out_;
    const int b2 = pi / 3, c = pi % 3;
    const size_t b0 = ((size_t)(2*b2)*C_ + c)*IMG + (size_t)(r0 + q)*N_ + t;
    const size_t b1 = b0 + (size_t)C_*IMG;
    #pragma unroll
    for (int n3=0;n3<8;++n3){ outf[b0 + (n3<<6)] = o[n3].x; outf[b1 + (n3<<6)] = o[n3].y; }
  }
}

// --------- 1/(otf*N^2) at digit-reversed (px, py) coordinates ---------------
__global__ __launch_bounds__(256) void rotf_kernel(
    const float* __restrict__ kerK, const float* __restrict__ rho,
    float* __restrict__ rotf)
{
  const int p = blockIdx.x * 256 + threadIdx.x;
  const int c = blockIdx.y;
  const int fx = drev9(p >> 9);
  const int fy = drev9(p & 511);
  float sy, cy, sx, cx;
  sincosf(-TWO_PI * (float)fy * (1.0f / 512.0f), &sy, &cy);
  sincosf(-TWO_PI * (float)fx * (1.0f / 512.0f), &sx, &cx);
  const float pyr[3] = {cy, 1.f, cy}, pyi[3] = {-sy, 0.f, sy};
  const float pxr[3] = {cx, 1.f, cx}, pxi[3] = {-sx, 0.f, sx};
  float acc = 0.f;
  for (int o = 0; o < KO_; ++o) {
    const int g = c * KO_ + o;
    float kr = 0.f, ki = 0.f;
    #pragma unroll
    for (int ky = 0; ky < 3; ++ky)
      #pragma unroll
      for (int kx = 0; kx < 3; ++kx) {
        float kv = kerK[g * 9 + ky * 3 + kx];
        float pr = pyr[ky] * pxr[kx] - pyi[ky] * pxi[kx];
        float pim = pyr[ky] * pxi[kx] + pyi[ky] * pxr[kx];
        kr += kv * pr; ki += kv * pim;
      }
    acc += rho[g] * (kr * kr + ki * ki);
  }
  rotf[(size_t)c * IMG + p] = 1.f / ((1.f + acc) * (float)(N_ * N_));
}

// ------------------------------ iter 0: w1 = x ------------------------------
__global__ __launch_bounds__(256) void pack_kernel(
    const float* __restrict__ x, float2* __restrict__ w1c)
{
  const int p = blockIdx.x * 256 + threadIdx.x;
  const int c = blockIdx.y, b2 = blockIdx.z;
  const float* x0 = x + ((size_t)(2 * b2) * C_ + c) * IMG;
  const float* x1 = x + ((size_t)(2 * b2 + 1) * C_ + c) * IMG;
  w1c[((size_t)b2 * C_ + c) * IMG + p] = make_float2(x0[p], x1[p]);
}

// -------- w1 = x + sum_o conv_circ(d_g, rho*flip(kerK_g)), d in fp16 --------
__global__ __launch_bounds__(256) void w1_kernel(
    const float* __restrict__ x, const __half2* __restrict__ d,
    const float* __restrict__ kerK, const float* __restrict__ rho,
    float2* __restrict__ w1c)
{
  const int p = blockIdx.x * 256 + threadIdx.x;
  const int c = blockIdx.y, b2 = blockIdx.z;
  const int y = p >> 9, xx = p & 511;
  const int ys[3] = {(y + 511) & 511, y, (y + 1) & 511};
  const int xs[3] = {(xx + 511) & 511, xx, (xx + 1) & 511};
  const float* x0 = x + ((size_t)(2 * b2) * C_ + c) * IMG;
  const float* x1 = x + ((size_t)(2 * b2 + 1) * C_ + c) * IMG;
  float s0 = x0[p], s1 = x1[p];
  #pragma unroll
  for (int o = 0; o < KO_; ++o) {
    const int g = c * KO_ + o;
    const float rg = rho[g];
    const __half2* dg = d + ((size_t)b2 * G_ + g) * IMG;
    #pragma unroll
    for (int i = 0; i < 3; ++i)
      #pragma unroll
      for (int j = 0; j < 3; ++j) {
        float wgt = rg * kerK[g * 9 + (2 - i) * 3 + (2 - j)];
        float2 v = __half22float2(dg[(size_t)ys[i] * N_ + xs[j]]);
        s0 += v.x * wgt; s1 += v.y * wgt;
      }
  }
  w1c[((size_t)b2 * C_ + c) * IMG + p] = make_float2(s0, s1);
}

// --- c = corr(u,kerK); t = c+mu; p' = soft(t); mu' = t-p'; d' = 2p'-t (fp16) --
__global__ __launch_bounds__(256) void update_kernel(
    const float2* __restrict__ uc, const float* __restrict__ kerK,
    const float* __restrict__ gamma, __half2* __restrict__ mu,
    __half2* __restrict__ d)
{
  const int p = blockIdx.x * 256 + threadIdx.x;
  const int c = blockIdx.y, b2 = blockIdx.z;
  const int y = p >> 9, xx = p & 511;
  const int ys[3] = {(y + 511) & 511, y, (y + 1) & 511};
  const int xs[3] = {(xx + 511) & 511, xx, (xx + 1) & 511};
  const float2* u = uc + ((size_t)b2 * C_ + c) * IMG;
  float2 tv[3][3];
  #pragma unroll
  for (int i = 0; i < 3; ++i)
    #pragma unroll
    for (int j = 0; j < 3; ++j)
      tv[i][j] = u[(size_t)ys[i] * N_ + xs[j]];
  #pragma unroll
  for (int o = 0; o < KO_; ++o) {
    const int g = c * KO_ + o;
    float cc0 = 0.f, cc1 = 0.f;
    #pragma unroll
    for (int i = 0; i < 3; ++i)
      #pragma unroll
      for (int j = 0; j < 3; ++j) {
        float wgt = kerK[g * 9 + i * 3 + j];
        cc0 += tv[i][j].x * wgt;
        cc1 += tv[i][j].y * wgt;
      }
    const size_t gi = ((size_t)b2 * G_ + g) * IMG + p;
    float2 m = __half22float2(mu[gi]);
    float t0 = cc0 + m.x, t1 = cc1 + m.y;
    float gam = gamma[g];
    float a0 = fabsf(t0) - gam;
    float a1 = fabsf(t1) - gam;
    float p0 = a0 > 0.f ? copysignf(a0, t0) : 0.f;
    float p1 = a1 > 0.f ? copysignf(a1, t1) : 0.f;
    mu[gi] = __floats2half2_rn(t0 - p0, t1 - p1);
    d[gi] = __floats2half2_rn(2.f * p0 - t0, 2.f * p1 - t1);
  }
}

__global__ void sentinel_kernel(float* out) { out[0] = 1.2e7f; }

extern "C" void kernel_launch(void* const* d_in, const int* in_sizes, int n_in,
                              void* d_out, int out_size, void* d_ws, size_t ws_size,
                              hipStream_t stream)
{
  const float* x     = (const float*)d_in[0];
  const float* kerK  = (const float*)d_in[1];
  const float* gamma = (const float*)d_in[2];
  const float* rho   = (const float*)d_in[3];
  float* out = (float*)d_out;
  float2* T0 = (float2*)d_out;   // d_out doubles as FFT ping buffer

  const size_t bufA_b = IMGPAIR * sizeof(float2);
  const size_t d_b    = GIMG * sizeof(__half2);
  const size_t rotf_b = (size_t)C_ * IMG * sizeof(float);
  const size_t mu_b   = GIMG * sizeof(__half2);
  const size_t need = bufA_b + d_b + rotf_b + mu_b;   // 154.1 MB

  if (ws_size < need) { sentinel_kernel<<<1, 1, 0, stream>>>(out); return; }

  char* w = (char*)d_ws;
  float2*  bufA  = (float2*)w;  w += bufA_b;
  __half2* dbuf  = (__half2*)w; w += d_b;
  float*   rotf  = (float*)w;   w += rotf_b;
  __half2* mubuf = (__half2*)w;

  hipMemsetAsync(mubuf, 0, mu_b, stream);

  const dim3 blk(256), blkF(512);
  const dim3 gridPix(1024, C_, P2_);
  const dim3 gridFFT(N_ / 8, P2_ * C_);

  rotf_kernel<<<dim3(1024, C_), blk, 0, stream>>>(kerK, rho, rotf);

  for (int it = 0; it < NITER_; ++it) {
    if (it == 0)
      pack_kernel<<<gridPix, blk, 0, stream>>>(x, bufA);
    else
      w1_kernel<<<gridPix, blk, 0, stream>>>(x, dbuf, kerK, rho, bufA);
    r8_fwdX<<<gridFFT, blkF, 0, stream>>>(bufA, T0);        // [y][x] -> [sx][y]
    r8_mid <<<gridFFT, blkF, 0, stream>>>(T0, bufA, rotf);  // -> [y][sx], filtered
    if (it < NITER_ - 1) {
      r8_invX<0><<<gridFFT, blkF, 0, stream>>>(bufA, (void*)T0);   // u in T0
      update_kernel<<<gridPix, blk, 0, stream>>>(T0, kerK, gamma, mubuf, dbuf);
    } else {
      r8_invX<1><<<gridFFT, blkF, 0, stream>>>(bufA, (void*)out);  // unpack
    }
  }
}

// Round 8
// 1070.320 us; speedup vs baseline: 1.8740x; 1.3563x over previous
//
#include <hip/hip_runtime.h>
#include <hip/hip_fp16.h>
#include <math.h>

// TVNet ADMM, radix-8 FFT + fused update/w1 edition.
// - FFT 512 = 8^3, 3 register stages; fwd DIF natural->digit-rev, inv DIT
//   digit-rev->natural; rotf (real, even, 1/((1+sum rho|K^|^2)N^2)) stored at
//   digit-reversed coords; image pairs packed as complex (exact by linearity).
// - All FFT intermediates (spectra, u) in fp16: |spec| <= ~3e3 << 65504;
//   per-pass 5e-4 rel error -> ~5e-3 abs on u (threshold 7.1e-2).
// - fused_uw: one tile kernel does {c=corr(u,K); t=c+mu; p=soft; mu'=t-p;
//   d'=2p-t; w1=x+sum rho*flip(K)*d'} with d' living only in LDS -> the d
//   buffer and its 100 MB/iter round trip are gone. mu ping-pongs (halo reads
//   of mu would race with neighbor-block mu' writes in a single buffer).
// - pack fused into fwdX<PACK=1> (reads x planes directly).
// WS: bufA(h2) 25.2 + rotf 3.1 + mu x2 100.6 = 129 MB. d_out doubles as T0.

namespace {
constexpr int C_ = 3, KO_ = 2, G_ = 6, N_ = 512, NITER_ = 10, P2_ = 8;
constexpr size_t IMG = (size_t)N_ * N_;
constexpr size_t IMGPAIR = (size_t)P2_ * C_ * IMG;
constexpr size_t GIMG = (size_t)P2_ * G_ * IMG;
constexpr float TWO_PI = 6.28318530717958647692f;
typedef __half2 h2;

__device__ __forceinline__ int drev9(int v) {  // digit-reverse base 8, 3 digits
  return ((v & 7) << 6) | (v & 56) | ((v >> 6) & 7);
}
__device__ __forceinline__ float2 cadd(float2 a, float2 b){ return make_float2(a.x+b.x, a.y+b.y); }
__device__ __forceinline__ float2 csub(float2 a, float2 b){ return make_float2(a.x-b.x, a.y-b.y); }
__device__ __forceinline__ float2 cmul(float2 a, float2 b){ return make_float2(a.x*b.x - a.y*b.y, a.x*b.y + a.y*b.x); }
template<int INV> __device__ __forceinline__ float2 rotm(float2 d){
  return INV ? make_float2(-d.y, d.x) : make_float2(d.y, -d.x);
}
__device__ __forceinline__ float2 to_f2(float2 v){ return v; }
__device__ __forceinline__ float2 to_f2(h2 v){ return __half22float2(v); }

// 8-point DFT, v natural in; out: v[idx] holds X[brev3(idx)]
template<int INV>
__device__ __forceinline__ void dft8(float2 v[8]) {
  constexpr float SQ = 0.70710678118654752440f;
  float2 a0=cadd(v[0],v[4]), d0=csub(v[0],v[4]);
  float2 a1=cadd(v[1],v[5]), d1=csub(v[1],v[5]);
  float2 a2=cadd(v[2],v[6]), d2=csub(v[2],v[6]);
  float2 a3=cadd(v[3],v[7]), d3=csub(v[3],v[7]);
  float2 b5 = INV ? make_float2(SQ*(d1.x-d1.y), SQ*(d1.y+d1.x))
                  : make_float2(SQ*(d1.x+d1.y), SQ*(d1.y-d1.x));
  float2 b6 = rotm<INV>(d2);
  float2 b7 = INV ? make_float2(-SQ*(d3.x+d3.y), SQ*(d3.x-d3.y))
                  : make_float2(SQ*(d3.y-d3.x), -SQ*(d3.x+d3.y));
  float2 c0=cadd(a0,a2), c2=csub(a0,a2);
  float2 c1=cadd(a1,a3), c3=rotm<INV>(csub(a1,a3));
  float2 c4=cadd(d0,b6), c6=csub(d0,b6);
  float2 c5=cadd(b5,b7), c7=rotm<INV>(csub(b5,b7));
  v[0]=cadd(c0,c1); v[1]=csub(c0,c1);
  v[2]=cadd(c2,c3); v[3]=csub(c2,c3);
  v[4]=cadd(c4,c5); v[5]=csub(c4,c5);
  v[6]=cadd(c6,c7); v[7]=csub(c6,c7);
}

// LDS: rows q (0..7) of 512; storage s -> block j=s>>6, rotated col (+8q).
__device__ __forceinline__ int laddr(int s, int q) {
  return (q << 9) | (s & 448) | ((s + 3 * (s >> 6) + (q << 3)) & 63);
}
__device__ __forceinline__ void lstore(float* lre, float* lim, int q, int s, float2 v){
  int a = laddr(s, q); lre[a] = v.x; lim[a] = v.y;
}
__device__ __forceinline__ float2 lload(const float* lre, const float* lim, int q, int s){
  int a = laddr(s, q); return make_float2(lre[a], lim[a]);
}

// forward stages 1..2, v pre-loaded (natural row data); leaves stage-2 in LDS
__device__ __forceinline__ void fwd_stage12v(float2 v[8], float* lre, float* lim, int t, int q) {
  constexpr int RB[8] = {0,4,2,6,1,5,3,7};
  dft8<0>(v);
  float sn, cs; sincosf(-TWO_PI * (1.0f/512.0f) * (float)t, &sn, &cs);
  float2 w = make_float2(cs, sn), tw = make_float2(1.f, 0.f);
  #pragma unroll
  for (int j=0;j<8;++j){ lstore(lre,lim,q,(j<<6)+t, cmul(v[RB[j]], tw)); tw = cmul(tw, w); }
  __syncthreads();
  const int jb = t >> 3, n1 = t & 7;
  #pragma unroll
  for (int m=0;m<8;++m) v[m] = lload(lre,lim,q,(jb<<6) + n1 + (m<<3));
  dft8<0>(v);
  sincosf(-TWO_PI * (1.0f/64.0f) * (float)n1, &sn, &cs);
  w = make_float2(cs, sn); tw = make_float2(1.f, 0.f);
  #pragma unroll
  for (int j2=0;j2<8;++j2){ lstore(lre,lim,q,(jb<<6)+(j2<<3)+n1, cmul(v[RB[j2]], tw)); tw = cmul(tw, w); }
  __syncthreads();
}

// inverse middle stage (LDS -> LDS), caller syncs around it
__device__ __forceinline__ void inv_stageB(float* lre, float* lim, int t, int q) {
  constexpr int RB[8] = {0,4,2,6,1,5,3,7};
  const int jb = t >> 3, n1 = t & 7;
  float sn, cs; sincosf(TWO_PI * (1.0f/64.0f) * (float)n1, &sn, &cs);
  float2 w = make_float2(cs, sn), tw = make_float2(1.f, 0.f);
  float2 v[8];
  #pragma unroll
  for (int j2=0;j2<8;++j2){ v[j2] = cmul(lload(lre,lim,q,(jb<<6)+n1+(j2<<3)), tw); tw = cmul(tw, w); }
  dft8<1>(v);
  #pragma unroll
  for (int n2=0;n2<8;++n2) lstore(lre,lim,q,(jb<<6)+(n2<<3)+n1, v[RB[n2]]);
}

// inverse last stage: LDS -> registers, natural order o[n3] = x[t + 64*n3]
__device__ __forceinline__ void inv_stageC(const float* lre, const float* lim,
                                           int t, int q, float2 o[8]) {
  constexpr int RB[8] = {0,4,2,6,1,5,3,7};
  float sn, cs; sincosf(TWO_PI * (1.0f/512.0f) * (float)t, &sn, &cs);
  float2 w = make_float2(cs, sn), tw = make_float2(1.f, 0.f);
  float2 v[8];
  #pragma unroll
  for (int j=0;j<8;++j){ v[j] = cmul(lload(lre,lim,q,(j<<6)+t), tw); tw = cmul(tw, w); }
  dft8<1>(v);
  #pragma unroll
  for (int n3=0;n3<8;++n3) o[n3] = v[RB[n3]];
}
} // namespace

// ---- pass 1: fwd-x; PACK=1 reads x planes directly, else h2 [y][x]; -> T0[sx][y] ----
template<int PACK>
__global__ __launch_bounds__(512) void r8_fwdX(
    const h2* __restrict__ in, const float* __restrict__ x, h2* __restrict__ out)
{
  __shared__ float lre[4096], lim[4096];
  const int tid = threadIdx.x, q = tid >> 6, t = tid & 63;
  const int pi = blockIdx.y, r0 = blockIdx.x << 3;
  constexpr int RB[8] = {0,4,2,6,1,5,3,7};
  float2 v[8];
  if (PACK) {
    const int b2 = pi / 3, c = pi % 3;
    const float* x0 = x + ((size_t)(2*b2)*C_ + c) * IMG + (size_t)(r0 + q) * N_;
    const float* x1 = x0 + (size_t)C_ * IMG;
    #pragma unroll
    for (int m=0;m<8;++m) v[m] = make_float2(x0[t+(m<<6)], x1[t+(m<<6)]);
  } else {
    const h2* src = in + (size_t)pi * IMG + (size_t)(r0 + q) * N_;
    #pragma unroll
    for (int m=0;m<8;++m) v[m] = to_f2(src[t+(m<<6)]);
  }
  fwd_stage12v(v, lre, lim, t, q);
  #pragma unroll
  for (int m=0;m<8;++m) v[m] = lload(lre,lim,q,(t<<3)+m);
  dft8<0>(v);
  #pragma unroll
  for (int k=0;k<8;++k) lstore(lre,lim,q,(t<<3)+k, v[RB[k]]);  // thread-exclusive slots
  __syncthreads();
  const int eq = tid & 7, e0 = tid >> 3;
  const size_t ob = (size_t)pi * IMG;
  #pragma unroll
  for (int kk=0;kk<8;++kk){
    int e = e0 + (kk<<6);
    int a = laddr(e, eq);
    out[ob + (size_t)e * N_ + r0 + eq] = __floats2half2_rn(lre[a], lim[a]);
  }
}

// ---- pass 2: fwd-y, *rotf (in regs), inv-y; T0[px][y] -> bufA[y][px] ----
__global__ __launch_bounds__(512) void r8_mid(
    const h2* __restrict__ in, h2* __restrict__ out,
    const float* __restrict__ rotf)
{
  __shared__ float lre[4096], lim[4096];
  const int tid = threadIdx.x, q = tid >> 6, t = tid & 63;
  const int pi = blockIdx.y, r0 = blockIdx.x << 3;
  const int c = pi % 3;
  constexpr int RB[8] = {0,4,2,6,1,5,3,7};
  const h2* src = in + (size_t)pi * IMG + (size_t)(r0 + q) * N_;
  float2 v[8];
  #pragma unroll
  for (int m=0;m<8;++m) v[m] = to_f2(src[t+(m<<6)]);
  fwd_stage12v(v, lre, lim, t, q);
  #pragma unroll
  for (int m=0;m<8;++m) v[m] = lload(lre,lim,q,(t<<3)+m);
  dft8<0>(v);
  const float* rc = rotf + (size_t)c * IMG + (size_t)(r0 + q) * N_ + (t<<3);
  const float4 g0 = *(const float4*)rc, g1 = *(const float4*)(rc + 4);
  const float gg[8] = {g0.x,g0.y,g0.z,g0.w,g1.x,g1.y,g1.z,g1.w};
  float2 xk[8];
  #pragma unroll
  for (int k=0;k<8;++k) xk[k] = make_float2(v[RB[k]].x*gg[k], v[RB[k]].y*gg[k]);
  dft8<1>(xk);                      // inverse stage A, register-only handoff
  #pragma unroll
  for (int n1=0;n1<8;++n1) lstore(lre,lim,q,(t<<3)+n1, xk[RB[n1]]);
  __syncthreads();
  inv_stageB(lre, lim, t, q);
  __syncthreads();
  float2 o[8];
  inv_stageC(lre, lim, t, q, o);
  #pragma unroll
  for (int n3=0;n3<8;++n3) lstore(lre,lim,q,(n3<<6)+t, o[n3]);  // natural y
  __syncthreads();
  const int eq = tid & 7, e0 = tid >> 3;
  const size_t ob = (size_t)pi * IMG;
  #pragma unroll
  for (int kk=0;kk<8;++kk){
    int e = e0 + (kk<<6);
    int a = laddr(e, eq);
    out[ob + (size_t)e * N_ + r0 + eq] = __floats2half2_rn(lre[a], lim[a]);
  }
}

// ---- pass 3: inv-x; bufA[y][sx] -> u h2 [y][x] (UNPACK: fp32 planes to out) ----
template<int UNPACK>
__global__ __launch_bounds__(512) void r8_invX(
    const h2* __restrict__ in, void* __restrict__ out_)
{
  __shared__ float lre[4096], lim[4096];
  const int tid = threadIdx.x, q = tid >> 6, t = tid & 63;
  const int pi = blockIdx.y, r0 = blockIdx.x << 3;
  constexpr int RB[8] = {0,4,2,6,1,5,3,7};
  const h2* src = in + (size_t)pi * IMG + (size_t)(r0 + q) * N_ + (t<<3);
  float2 v[8];
  #pragma unroll
  for (int m=0;m<8;++m) v[m] = to_f2(src[m]);
  dft8<1>(v);
  #pragma unroll
  for (int n1=0;n1<8;++n1) lstore(lre,lim,q,(t<<3)+n1, v[RB[n1]]);
  __syncthreads();
  inv_stageB(lre, lim, t, q);
  __syncthreads();
  float2 o[8];
  inv_stageC(lre, lim, t, q, o);
  if (!UNPACK) {
    h2* out = (h2*)out_;
    const size_t base = (size_t)pi * IMG + (size_t)(r0 + q) * N_ + t;
    #pragma unroll
    for (int n3=0;n3<8;++n3) out[base + (n3<<6)] = __floats2half2_rn(o[n3].x, o[n3].y);
  } else {
    float* outf = (float*)out_;
    const int b2 = pi / 3, c = pi % 3;
    const size_t b0 = ((size_t)(2*b2)*C_ + c)*IMG + (size_t)(r0 + q)*N_ + t;
    const size_t b1 = b0 + (size_t)C_*IMG;
    #pragma unroll
    for (int n3=0;n3<8;++n3){ outf[b0 + (n3<<6)] = o[n3].x; outf[b1 + (n3<<6)] = o[n3].y; }
  }
}

// ---- fused update+w1: u (h2, natural) -> mu' (ping-pong) and next w1 (h2) ----
// d' = 2*soft(corr(u,K)+mu) - (corr(u,K)+mu) lives only in LDS.
__global__ __launch_bounds__(256) void fused_uw(
    const h2* __restrict__ u, const float* __restrict__ x,
    const float* __restrict__ kerK, const float* __restrict__ gamma,
    const float* __restrict__ rho,
    const h2* __restrict__ muIn, h2* __restrict__ muOut,
    h2* __restrict__ w1)
{
  __shared__ float2 uL[36][37];        // u tile, halo 2
  __shared__ float2 dL[KO_][34][35];   // d' tile, halo 1
  const int tid = threadIdx.x;
  const int tx0 = blockIdx.x << 5, ty0 = blockIdx.y << 5;
  const int pi = blockIdx.z, b2 = pi / 3, c = pi % 3;
  const h2* up = u + (size_t)pi * IMG;

  for (int idx = tid; idx < 36*36; idx += 256) {
    int r = idx / 36, cc = idx - r * 36;
    int gy = (ty0 + r - 2) & 511, gx = (tx0 + cc - 2) & 511;
    uL[r][cc] = __half22float2(up[(size_t)gy * N_ + gx]);
  }
  float k0[KO_][9], gam[KO_], rg[KO_];
  #pragma unroll
  for (int o = 0; o < KO_; ++o) {
    const int g = c * KO_ + o;
    #pragma unroll
    for (int q = 0; q < 9; ++q) k0[o][q] = kerK[g*9+q];
    gam[o] = gamma[g]; rg[o] = rho[g];
  }
  __syncthreads();

  for (int idx = tid; idx < 34*34; idx += 256) {
    int r = idx / 34, cc = idx - r * 34;          // d' at rel (r-1, cc-1)
    int gy = (ty0 + r - 1) & 511, gx = (tx0 + cc - 1) & 511;
    const bool own = (r >= 1) & (r <= 32) & (cc >= 1) & (cc <= 32);
    #pragma unroll
    for (int o = 0; o < KO_; ++o) {
      float c0 = 0.f, c1 = 0.f;
      #pragma unroll
      for (int i = 0; i < 3; ++i)
        #pragma unroll
        for (int j = 0; j < 3; ++j) {
          float wgt = k0[o][i*3+j];                // cross-correlation
          float2 v = uL[r + i][cc + j];
          c0 += v.x * wgt; c1 += v.y * wgt;
        }
      const size_t gi = ((size_t)b2 * G_ + (c*KO_+o)) * IMG + (size_t)gy * N_ + gx;
      float2 m = __half22float2(muIn[gi]);
      float t0 = c0 + m.x, t1 = c1 + m.y;
      float a0 = fabsf(t0) - gam[o], a1 = fabsf(t1) - gam[o];
      float p0 = a0 > 0.f ? copysignf(a0, t0) : 0.f;
      float p1 = a1 > 0.f ? copysignf(a1, t1) : 0.f;
      if (own) muOut[gi] = __floats2half2_rn(t0 - p0, t1 - p1);
      dL[o][r][cc] = make_float2(2.f*p0 - t0, 2.f*p1 - t1);
    }
  }
  __syncthreads();

  const int lx = tid & 31, ly0 = tid >> 5;
  const size_t xb0 = ((size_t)(2*b2)*C_ + c) * IMG;
  const size_t xb1 = xb0 + (size_t)C_ * IMG;
  #pragma unroll
  for (int k = 0; k < 4; ++k) {
    const int oy = ly0 + (k << 3), ox = lx;
    const size_t gp = (size_t)(ty0 + oy) * N_ + (tx0 + ox);
    float s0 = x[xb0 + gp], s1 = x[xb1 + gp];
    #pragma unroll
    for (int o = 0; o < KO_; ++o) {
      float a0 = 0.f, a1 = 0.f;
      #pragma unroll
      for (int i = 0; i < 3; ++i)
        #pragma unroll
        for (int j = 0; j < 3; ++j) {
          float wgt = k0[o][(2-i)*3 + (2-j)];      // adjoint = flipped
          float2 v = dL[o][oy + i][ox + j];
          a0 += v.x * wgt; a1 += v.y * wgt;
        }
      s0 += rg[o] * a0; s1 += rg[o] * a1;
    }
    w1[(size_t)pi * IMG + gp] = __floats2half2_rn(s0, s1);
  }
}

// --------- 1/(otf*N^2) at digit-reversed (px, py) coordinates ---------------
__global__ __launch_bounds__(256) void rotf_kernel(
    const float* __restrict__ kerK, const float* __restrict__ rho,
    float* __restrict__ rotf)
{
  const int p = blockIdx.x * 256 + threadIdx.x;
  const int c = blockIdx.y;
  const int fx = drev9(p >> 9);
  const int fy = drev9(p & 511);
  float sy, cy, sx, cx;
  sincosf(-TWO_PI * (float)fy * (1.0f / 512.0f), &sy, &cy);
  sincosf(-TWO_PI * (float)fx * (1.0f / 512.0f), &sx, &cx);
  const float pyr[3] = {cy, 1.f, cy}, pyi[3] = {-sy, 0.f, sy};
  const float pxr[3] = {cx, 1.f, cx}, pxi[3] = {-sx, 0.f, sx};
  float acc = 0.f;
  for (int o = 0; o < KO_; ++o) {
    const int g = c * KO_ + o;
    float kr = 0.f, ki = 0.f;
    #pragma unroll
    for (int ky = 0; ky < 3; ++ky)
      #pragma unroll
      for (int kx = 0; kx < 3; ++kx) {
        float kv = kerK[g * 9 + ky * 3 + kx];
        float pr = pyr[ky] * pxr[kx] - pyi[ky] * pxi[kx];
        float pim = pyr[ky] * pxi[kx] + pyi[ky] * pxr[kx];
        kr += kv * pr; ki += kv * pim;
      }
    acc += rho[g] * (kr * kr + ki * ki);
  }
  rotf[(size_t)c * IMG + p] = 1.f / ((1.f + acc) * (float)(N_ * N_));
}

__global__ void sentinel_kernel(float* out) { out[0] = 1.2e7f; }

extern "C" void kernel_launch(void* const* d_in, const int* in_sizes, int n_in,
                              void* d_out, int out_size, void* d_ws, size_t ws_size,
                              hipStream_t stream)
{
  const float* x     = (const float*)d_in[0];
  const float* kerK  = (const float*)d_in[1];
  const float* gamma = (const float*)d_in[2];
  const float* rho   = (const float*)d_in[3];
  float* out = (float*)d_out;
  h2* T0 = (h2*)d_out;   // d_out doubles as FFT ping / u buffer (h2 needs half)

  const size_t bufA_b = IMGPAIR * sizeof(h2);              // 25.2 MB
  const size_t rotf_b = (size_t)C_ * IMG * sizeof(float);  // 3.15 MB
  const size_t mu_b   = GIMG * sizeof(h2);                 // 50.33 MB
  const size_t need = bufA_b + rotf_b + 2 * mu_b;          // 128.9 MB

  if (ws_size < need) { sentinel_kernel<<<1, 1, 0, stream>>>(out); return; }

  char* w = (char*)d_ws;
  h2*    bufA = (h2*)w;    w += bufA_b;
  float* rotf = (float*)w; w += rotf_b;
  h2*    mu0  = (h2*)w;    w += mu_b;
  h2*    mu1  = (h2*)w;

  hipMemsetAsync(mu0, 0, mu_b, stream);   // mu = 0 at iter 0

  const dim3 blk(256), blkF(512);
  const dim3 gridFFT(N_ / 8, P2_ * C_);
  const dim3 gridT(16, 16, P2_ * C_);

  rotf_kernel<<<dim3(1024, C_), blk, 0, stream>>>(kerK, rho, rotf);

  // solve 0 (w1 = x, packed on the fly)
  r8_fwdX<1><<<gridFFT, blkF, 0, stream>>>(nullptr, x, T0);
  r8_mid<<<gridFFT, blkF, 0, stream>>>(T0, bufA, rotf);

  h2* muIn = mu0; h2* muOut = mu1;
  for (int it = 1; it < NITER_; ++it) {
    r8_invX<0><<<gridFFT, blkF, 0, stream>>>(bufA, (void*)T0);          // u (h2)
    fused_uw<<<gridT, blk, 0, stream>>>(T0, x, kerK, gamma, rho,
                                        muIn, muOut, bufA);             // next w1
    r8_fwdX<0><<<gridFFT, blkF, 0, stream>>>(bufA, nullptr, T0);
    r8_mid<<<gridFFT, blkF, 0, stream>>>(T0, bufA, rotf);
    h2* tmp = muIn; muIn = muOut; muOut = tmp;
  }
  r8_invX<1><<<gridFFT, blkF, 0, stream>>>(bufA, (void*)out);           // unpack
}